// Round 1
// baseline (261.007 us; speedup 1.0000x reference)
//
#include <hip/hip_runtime.h>
#include <math.h>

// Problem constants (fixed shapes from setup_inputs)
//  B=4, N=16384, C_img=C_lidar=64, K=1024 (img_size), D1=128, D2=64
#define NPTS   16384
#define BN_TOT 65536
#define INV_BN (1.f/65536.f)
#define EPSF   1e-5f

// ---------------------------------------------------------------- k_pool: g[b,c] = mean_k img[b,c,k]
__global__ __launch_bounds__(256) void k_pool(const float* __restrict__ img, float* __restrict__ g) {
    __shared__ float red[256];
    const int bc = blockIdx.x;          // b*64 + c
    const int t = threadIdx.x;
    float s = 0.f;
    #pragma unroll
    for (int k = t; k < 1024; k += 256) s += img[bc*1024 + k];
    red[t] = s;
    __syncthreads();
    for (int w = 128; w > 0; w >>= 1) {
        if (t < w) red[t] += red[t + w];
        __syncthreads();
    }
    if (t == 0) g[bc] = red[0] * (1.f/1024.f);
}

// ---------------------------------------------------------------- k_c1: c1[b,o] = b1[o] + sum_{c<64} g[b,c]*W1[o,c]
__global__ __launch_bounds__(512) void k_c1(const float* __restrict__ g, const float* __restrict__ W1,
                                            const float* __restrict__ b1, float* __restrict__ c1) {
    const int t = threadIdx.x;          // 512 threads: b = t>>7, o = t&127
    const int b = t >> 7, o = t & 127;
    float s = b1[o];
    #pragma unroll 8
    for (int c = 0; c < 64; ++c) s += g[b*64 + c] * W1[o*128 + c];
    c1[t] = s;                          // t == b*128 + o
}

// ---------------------------------------------------------------- k_M: M[b,c,j] = (1/K) sum_k W3[k,j]*img[b,c,k];  d[b,c] = (1/K) sum_k b3[k]*img[b,c,k]
__global__ __launch_bounds__(256) void k_M(const float* __restrict__ img, const float* __restrict__ W3,
                                           const float* __restrict__ b3, float* __restrict__ M,
                                           float* __restrict__ dv) {
    __shared__ float imgs[1024];
    __shared__ float mr[4][64];
    __shared__ float dred[256];
    const int bc = blockIdx.x;          // b*64 + c
    const int t = threadIdx.x;
    for (int k = t; k < 1024; k += 256) imgs[k] = img[bc*1024 + k];
    __syncthreads();
    const int j = t & 63, kk = t >> 6;
    float a = 0.f;
    #pragma unroll 4
    for (int k = kk*256; k < kk*256 + 256; ++k) a += imgs[k] * W3[k*64 + j];
    mr[kk][j] = a;
    float d = 0.f;
    #pragma unroll 4
    for (int k = t; k < 1024; k += 256) d += b3[k] * imgs[k];
    dred[t] = d;
    __syncthreads();
    if (t < 64) M[bc*64 + t] = (mr[0][t] + mr[1][t] + mr[2][t] + mr[3][t]) * (1.f/1024.f);
    for (int w = 128; w > 0; w >>= 1) {
        if (t < w) dred[t] += dred[t + w];
        __syncthreads();
    }
    if (t == 0) dv[bc] = dred[0] * (1.f/1024.f);
}

// ---------------------------------------------------------------- GEMM1: y1[row,o] = sum_{c<64} lidar[row,c]*W1[o,64+c] + c1[b,o]; accumulate BN stats
// 32 rows x 128 outs per block, 256 threads, 4x4 register tile
__global__ __launch_bounds__(256) void k_gemm1(const float* __restrict__ lidar,
        const float* __restrict__ W1, const float* __restrict__ c1,
        float* __restrict__ y1, float* __restrict__ st) {
    __shared__ float Ls[64][36];    // [c][row], padded
    __shared__ float Ws[64][132];   // [c][o],   padded
    __shared__ float red[8][128];
    const int t = threadIdx.x;
    const int base = blockIdx.x * 32;
    const int b = base >> 14;       // /16384
    for (int i = t; i < 32*64; i += 256) {
        int r = i >> 6, c = i & 63;
        Ls[c][r] = lidar[(base + r)*64 + c];
    }
    for (int i = t; i < 128*64; i += 256) {
        int o = i >> 6, c = i & 63;
        Ws[c][o] = W1[o*128 + 64 + c];
    }
    __syncthreads();
    const int og = (t & 31) * 4;
    const int rg = (t >> 5) * 4;
    float acc[4][4] = {};
    #pragma unroll 4
    for (int c = 0; c < 64; ++c) {
        float la[4], wa[4];
        *(float4*)la = *(const float4*)&Ls[c][rg];
        *(float4*)wa = *(const float4*)&Ws[c][og];
        #pragma unroll
        for (int ri = 0; ri < 4; ++ri)
            #pragma unroll
            for (int oi = 0; oi < 4; ++oi)
                acc[ri][oi] += la[ri] * wa[oi];
    }
    float cb[4];
    *(float4*)cb = *(const float4*)&c1[b*128 + og];
    float s[4] = {0,0,0,0}, q[4] = {0,0,0,0};
    #pragma unroll
    for (int ri = 0; ri < 4; ++ri) {
        float v[4];
        #pragma unroll
        for (int oi = 0; oi < 4; ++oi) {
            v[oi] = acc[ri][oi] + cb[oi];
            s[oi] += v[oi];
            q[oi] += v[oi] * v[oi];
        }
        *(float4*)&y1[(base + rg + ri)*128 + og] = *(float4*)v;
    }
    #pragma unroll
    for (int oi = 0; oi < 4; ++oi) red[t >> 5][og + oi] = s[oi];
    __syncthreads();
    if (t < 128) {
        float a = 0.f;
        #pragma unroll
        for (int k = 0; k < 8; ++k) a += red[k][t];
        atomicAdd(&st[t], a);
    }
    __syncthreads();
    #pragma unroll
    for (int oi = 0; oi < 4; ++oi) red[t >> 5][og + oi] = q[oi];
    __syncthreads();
    if (t < 128) {
        float a = 0.f;
        #pragma unroll
        for (int k = 0; k < 8; ++k) a += red[k][t];
        atomicAdd(&st[128 + t], a);
    }
}

// ---------------------------------------------------------------- k_fin1: scale/shift from stats
__global__ void k_fin1(const float* __restrict__ st, const float* __restrict__ g1,
                       const float* __restrict__ be1, float* __restrict__ sc) {
    const int o = threadIdx.x;  // 128
    float mu = st[o] * INV_BN;
    float var = st[128 + o] * INV_BN - mu * mu;
    float s = g1[o] * rsqrtf(var + EPSF);
    sc[o] = s;
    sc[128 + o] = be1[o] - mu * s;
}

// ---------------------------------------------------------------- GEMM2: y2[row,j] = sum_o relu(bn1(y1))[row,o]*W2[j,o] + b2[j]; accumulate BN stats
// 32 rows x 64 outs per block, 256 threads, 2x4 register tile
__global__ __launch_bounds__(256) void k_gemm2(const float* __restrict__ y1,
        const float* __restrict__ W2, const float* __restrict__ b2,
        const float* __restrict__ sc, float* __restrict__ y2, float* __restrict__ st2) {
    __shared__ float Ys[128][36];   // [o][row]
    __shared__ float Ws[128][68];   // [o][j]
    __shared__ float red[16][64];
    const int t = threadIdx.x;
    const int base = blockIdx.x * 32;
    for (int i = t; i < 32*128; i += 256) {
        int r = i >> 7, o = i & 127;
        float v = y1[(base + r)*128 + o];
        v = v * sc[o] + sc[128 + o];
        Ys[o][r] = fmaxf(v, 0.f);
    }
    for (int i = t; i < 64*128; i += 256) {
        int j = i >> 7, o = i & 127;
        Ws[o][j] = W2[j*128 + o];
    }
    __syncthreads();
    const int jg = (t & 15) * 4;
    const int rg = (t >> 4) * 2;
    float acc[2][4] = {};
    #pragma unroll 4
    for (int o = 0; o < 128; ++o) {
        float ya[2], wa[4];
        *(float2*)ya = *(const float2*)&Ys[o][rg];
        *(float4*)wa = *(const float4*)&Ws[o][jg];
        #pragma unroll
        for (int ri = 0; ri < 2; ++ri)
            #pragma unroll
            for (int ji = 0; ji < 4; ++ji)
                acc[ri][ji] += ya[ri] * wa[ji];
    }
    float bb[4];
    *(float4*)bb = *(const float4*)&b2[jg];
    float s[4] = {0,0,0,0}, q[4] = {0,0,0,0};
    #pragma unroll
    for (int ri = 0; ri < 2; ++ri) {
        float v[4];
        #pragma unroll
        for (int ji = 0; ji < 4; ++ji) {
            v[ji] = acc[ri][ji] + bb[ji];
            s[ji] += v[ji];
            q[ji] += v[ji] * v[ji];
        }
        *(float4*)&y2[(base + rg + ri)*64 + jg] = *(float4*)v;
    }
    #pragma unroll
    for (int ji = 0; ji < 4; ++ji) red[t >> 4][jg + ji] = s[ji];
    __syncthreads();
    if (t < 64) {
        float a = 0.f;
        #pragma unroll
        for (int k = 0; k < 16; ++k) a += red[k][t];
        atomicAdd(&st2[t], a);
    }
    __syncthreads();
    #pragma unroll
    for (int ji = 0; ji < 4; ++ji) red[t >> 4][jg + ji] = q[ji];
    __syncthreads();
    if (t < 64) {
        float a = 0.f;
        #pragma unroll
        for (int k = 0; k < 16; ++k) a += red[k][t];
        atomicAdd(&st2[64 + t], a);
    }
}

// ---------------------------------------------------------------- k_fin2
__global__ void k_fin2(const float* __restrict__ st2, const float* __restrict__ g2,
                       const float* __restrict__ be2, float* __restrict__ sc2) {
    const int o = threadIdx.x;  // 64
    float mu = st2[o] * INV_BN;
    float var = st2[64 + o] * INV_BN - mu * mu;
    float s = g2[o] * rsqrtf(var + EPSF);
    sc2[o] = s;
    sc2[64 + o] = be2[o] - mu * s;
}

// ---------------------------------------------------------------- GEMM3: out[row,c] = sum_j relu(bn2(y2))[row,j]*M[b,c,j] + d[b,c]
// 64 rows x 64 outs per block, 256 threads, 4x4 register tile
__global__ __launch_bounds__(256) void k_gemm3(const float* __restrict__ y2,
        const float* __restrict__ M, const float* __restrict__ dv,
        const float* __restrict__ sc2, float* __restrict__ out) {
    __shared__ float Ys[64][68];    // [j][row]
    __shared__ float Ms[64][68];    // [j][c]
    const int t = threadIdx.x;
    const int base = blockIdx.x * 64;
    const int b = base >> 14;
    for (int i = t; i < 64*64; i += 256) {
        int r = i >> 6, j = i & 63;
        float v = y2[(base + r)*64 + j];
        v = v * sc2[j] + sc2[64 + j];
        Ys[j][r] = fmaxf(v, 0.f);
    }
    for (int i = t; i < 64*64; i += 256) {
        int c = i >> 6, j = i & 63;
        Ms[j][c] = M[(b*64 + c)*64 + j];
    }
    __syncthreads();
    const int cg = (t & 15) * 4;
    const int rg = (t >> 4) * 4;
    float acc[4][4] = {};
    #pragma unroll 4
    for (int j = 0; j < 64; ++j) {
        float ya[4], ma[4];
        *(float4*)ya = *(const float4*)&Ys[j][rg];
        *(float4*)ma = *(const float4*)&Ms[j][cg];
        #pragma unroll
        for (int ri = 0; ri < 4; ++ri)
            #pragma unroll
            for (int ci = 0; ci < 4; ++ci)
                acc[ri][ci] += ya[ri] * ma[ci];
    }
    float db[4];
    *(float4*)db = *(const float4*)&dv[b*64 + cg];
    #pragma unroll
    for (int ri = 0; ri < 4; ++ri) {
        float v[4];
        #pragma unroll
        for (int ci = 0; ci < 4; ++ci) v[ci] = acc[ri][ci] + db[ci];
        *(float4*)&out[(base + rg + ri)*64 + cg] = *(float4*)v;
    }
}

// ----------------------------------------------------------------
extern "C" void kernel_launch(void* const* d_in, const int* in_sizes, int n_in,
                              void* d_out, int out_size, void* d_ws, size_t ws_size,
                              hipStream_t stream) {
    const float* lidar = (const float*)d_in[0];   // [4,16384,64]
    const float* img   = (const float*)d_in[1];   // [4,64,16,64] -> [4,64,1024]
    const float* W1  = (const float*)d_in[2];     // [128,128]
    const float* b1  = (const float*)d_in[3];
    const float* g1  = (const float*)d_in[4];
    const float* be1 = (const float*)d_in[5];
    const float* W2  = (const float*)d_in[6];     // [64,128]
    const float* b2  = (const float*)d_in[7];
    const float* g2  = (const float*)d_in[8];
    const float* be2 = (const float*)d_in[9];
    const float* W3  = (const float*)d_in[10];    // [1024,64]
    const float* b3  = (const float*)d_in[11];

    float* ws = (float*)d_ws;
    float* y1 = ws;                    // 65536*128
    float* y2 = y1 + 65536*128;        // 65536*64
    float* g  = y2 + 65536*64;         // 256
    float* c1 = g  + 256;              // 512
    float* M  = c1 + 512;              // 16384
    float* dv = M  + 16384;            // 256
    float* st = dv + 256;              // 384 = sum1[128] sq1[128] sum2[64] sq2[64]
    float* sc = st + 384;              // 384 = scale1[128] shift1[128] scale2[64] shift2[64]

    hipMemsetAsync(st, 0, 384 * sizeof(float), stream);

    k_pool <<<256,  256, 0, stream>>>(img, g);
    k_c1   <<<1,    512, 0, stream>>>(g, W1, b1, c1);
    k_M    <<<256,  256, 0, stream>>>(img, W3, b3, M, dv);
    k_gemm1<<<2048, 256, 0, stream>>>(lidar, W1, c1, y1, st);
    k_fin1 <<<1,    128, 0, stream>>>(st, g1, be1, sc);
    k_gemm2<<<2048, 256, 0, stream>>>(y1, W2, b2, sc, y2, st + 256);
    k_fin2 <<<1,    64,  0, stream>>>(st + 256, g2, be2, sc + 256);
    k_gemm3<<<1024, 256, 0, stream>>>(y2, M, dv, sc + 256, (float*)d_out);
}

// Round 2
// 203.823 us; speedup vs baseline: 1.2806x; 1.2806x over previous
//
#include <hip/hip_runtime.h>
#include <math.h>

// Shapes: B=4, N=16384 (NROW=65536 rows), C=64, K=1024, D1=128, D2=64
#define NROW   65536
#define INV_BN (1.f/65536.f)
#define EPSF   1e-5f
#define PAD1   132     // word stride for lidar K-major tile

// ------------------------------------------------------------------ k_prep
// per (b,c): g[bc]=mean_k img; dv[bc]=(1/K)sum_k b3[k]*img; MT[b][j][c]=(1/K)sum_k W3[k][j]*img[bc][k]
__global__ __launch_bounds__(256) void k_prep(const float* __restrict__ img,
        const float* __restrict__ W3, const float* __restrict__ b3,
        float* __restrict__ g, float* __restrict__ MT, float* __restrict__ dv) {
    __shared__ float imgs[1024];
    __shared__ float mr[4][64];
    __shared__ float red[256];
    __shared__ float red2[256];
    const int bc = blockIdx.x;
    const int t = threadIdx.x;
    const int b = bc >> 6, c = bc & 63;
    for (int k = t; k < 1024; k += 256) imgs[k] = img[bc*1024 + k];
    __syncthreads();
    const int j = t & 63, kk = t >> 6;
    float a = 0.f;
    #pragma unroll 4
    for (int k = kk*256; k < kk*256 + 256; ++k) a += imgs[k] * W3[k*64 + j];
    mr[kk][j] = a;
    float d = 0.f, s = 0.f;
    #pragma unroll 4
    for (int k = t; k < 1024; k += 256) { d += b3[k]*imgs[k]; s += imgs[k]; }
    red[t] = d; red2[t] = s;
    __syncthreads();
    if (t < 64) MT[(b*64 + t)*64 + c] = (mr[0][t]+mr[1][t]+mr[2][t]+mr[3][t]) * (1.f/1024.f);
    for (int w = 128; w > 0; w >>= 1) {
        if (t < w) { red[t] += red[t+w]; red2[t] += red2[t+w]; }
        __syncthreads();
    }
    if (t == 0) { dv[bc] = red[0]*(1.f/1024.f); g[bc] = red2[0]*(1.f/1024.f); }
}

// ------------------------------------------------------------------ k_wt: weight transposes + c1
__global__ __launch_bounds__(512) void k_wt(const float* __restrict__ W1,
        const float* __restrict__ W2, const float* __restrict__ b1,
        const float* __restrict__ g, float* __restrict__ W1hT,
        float* __restrict__ W2T, float* __restrict__ c1) {
    const int t = threadIdx.x;
    for (int i = t; i < 8192; i += 512) {           // W1hT[c][o] = W1[o][64+c]
        int c = i >> 7, o = i & 127;
        W1hT[i] = W1[o*128 + 64 + c];
    }
    for (int i = t; i < 8192; i += 512) {           // W2T[o][j] = W2[j][o]
        int o = i >> 6, jj = i & 63;
        W2T[i] = W2[jj*128 + o];
    }
    const int b = t >> 7, o = t & 127;              // c1[b][o]
    float s = b1[o];
    #pragma unroll 8
    for (int c = 0; c < 64; ++c) s += g[b*64 + c] * W1[o*128 + c];
    c1[t] = s;
}

// ------------------------------------------------------------------ GEMM1: 128 rows x 128 outs / block
// y1T[o][row] = sum_c lidar[row][c]*W1hT[c][o] + c1[b][o]; stats atomics
__global__ __launch_bounds__(256) void k_gemm1(const float* __restrict__ lidar,
        const float* __restrict__ W1hT, const float* __restrict__ c1,
        float* __restrict__ y1T, float* __restrict__ st) {
    __shared__ __align__(16) float Lt[64*PAD1];   // [c][row] padded
    __shared__ __align__(16) float Ws[64*128];    // [c][o]
    const int t = threadIdx.x;
    const int base = blockIdx.x * 128;
    const int b = base >> 14;
    {   // stage lidar transposed: coalesced reads, one-time strided LDS writes
        const int c = t & 63, r0 = (t >> 6) * 32;
        #pragma unroll 8
        for (int i = 0; i < 32; ++i)
            Lt[c*PAD1 + r0 + i] = lidar[(base + r0 + i)*64 + c];
    }
    for (int f = t; f < 2048; f += 256)           // linear copy W1hT
        *(float4*)&Ws[f*4] = *(const float4*)&W1hT[f*4];
    __syncthreads();

    const int rg = (t & 15) * 8, og = (t >> 4) * 8;
    float acc[8][8] = {};
    #pragma unroll 2
    for (int c = 0; c < 64; ++c) {
        float la[8], wa[8];
        *(float4*)&la[0] = *(const float4*)&Lt[c*PAD1 + rg];
        *(float4*)&la[4] = *(const float4*)&Lt[c*PAD1 + rg + 4];
        *(float4*)&wa[0] = *(const float4*)&Ws[c*128 + og];
        *(float4*)&wa[4] = *(const float4*)&Ws[c*128 + og + 4];
        #pragma unroll
        for (int ri = 0; ri < 8; ++ri)
            #pragma unroll
            for (int oi = 0; oi < 8; ++oi)
                acc[ri][oi] += la[ri] * wa[oi];
    }
    float cb[8];
    *(float4*)&cb[0] = *(const float4*)&c1[b*128 + og];
    *(float4*)&cb[4] = *(const float4*)&c1[b*128 + og + 4];
    float s[8] = {}, q[8] = {};
    #pragma unroll
    for (int ri = 0; ri < 8; ++ri)
        #pragma unroll
        for (int oi = 0; oi < 8; ++oi) {
            float v = acc[ri][oi] + cb[oi];
            acc[ri][oi] = v; s[oi] += v; q[oi] += v*v;
        }
    #pragma unroll
    for (int oi = 0; oi < 8; ++oi) {              // coalesced along rows
        float4 v0 = {acc[0][oi],acc[1][oi],acc[2][oi],acc[3][oi]};
        float4 v1 = {acc[4][oi],acc[5][oi],acc[6][oi],acc[7][oi]};
        *(float4*)&y1T[(og+oi)*NROW + base + rg]     = v0;
        *(float4*)&y1T[(og+oi)*NROW + base + rg + 4] = v1;
    }
    __syncthreads();                               // Lt dead -> reuse as reduce scratch
    float* red = Lt;
    const int rgi = t & 15;
    #pragma unroll
    for (int oi = 0; oi < 8; ++oi) red[rgi*128 + og + oi] = s[oi];
    __syncthreads();
    if (t < 128) { float a = 0.f;
        #pragma unroll
        for (int k = 0; k < 16; ++k) a += red[k*128 + t];
        atomicAdd(&st[t], a); }
    __syncthreads();
    #pragma unroll
    for (int oi = 0; oi < 8; ++oi) red[rgi*128 + og + oi] = q[oi];
    __syncthreads();
    if (t < 128) { float a = 0.f;
        #pragma unroll
        for (int k = 0; k < 16; ++k) a += red[k*128 + t];
        atomicAdd(&st[128 + t], a); }
}

// ------------------------------------------------------------------ k_fin1/k_fin2
__global__ void k_fin1(const float* __restrict__ st, const float* __restrict__ g1,
                       const float* __restrict__ be1, float* __restrict__ sc) {
    const int o = threadIdx.x;  // 128
    float mu = st[o] * INV_BN;
    float var = st[128 + o] * INV_BN - mu*mu;
    float s = g1[o] * rsqrtf(var + EPSF);
    sc[o] = s; sc[128 + o] = be1[o] - mu*s;
}
__global__ void k_fin2(const float* __restrict__ st2, const float* __restrict__ g2,
                       const float* __restrict__ be2, float* __restrict__ sc2) {
    const int o = threadIdx.x;  // 64
    float mu = st2[o] * INV_BN;
    float var = st2[64 + o] * INV_BN - mu*mu;
    float s = g2[o] * rsqrtf(var + EPSF);
    sc2[o] = s; sc2[64 + o] = be2[o] - mu*s;
}

// ------------------------------------------------------------------ GEMM2: 64 rows x 64 outs / block
// y2T[j][row] = sum_o relu(bn1(y1T[o][row]))*W2T[o][j] + b2[j]; stats atomics
__global__ __launch_bounds__(256) void k_gemm2(const float* __restrict__ y1T,
        const float* __restrict__ W2T, const float* __restrict__ sc,
        const float* __restrict__ b2, float* __restrict__ y2T, float* __restrict__ st2) {
    __shared__ __align__(16) float Ys[128*64];   // [o][row]
    __shared__ __align__(16) float Ws[128*64];   // [o][j]
    const int t = threadIdx.x;
    const int base = blockIdx.x * 64;
    for (int f = t; f < 2048; f += 256) {        // contiguous stage + bn1 + relu
        int o = f >> 4, r4 = (f & 15) * 4;
        float4 v = *(const float4*)&y1T[o*NROW + base + r4];
        float scl = sc[o], sh = sc[128 + o];
        v.x = fmaxf(v.x*scl + sh, 0.f); v.y = fmaxf(v.y*scl + sh, 0.f);
        v.z = fmaxf(v.z*scl + sh, 0.f); v.w = fmaxf(v.w*scl + sh, 0.f);
        *(float4*)&Ys[o*64 + r4] = v;
    }
    for (int f = t; f < 2048; f += 256)
        *(float4*)&Ws[f*4] = *(const float4*)&W2T[f*4];
    __syncthreads();

    const int rg = (t & 15) * 4, jg = (t >> 4) * 4;
    float acc[4][4] = {};
    #pragma unroll 4
    for (int o = 0; o < 128; ++o) {
        float ya[4], wa[4];
        *(float4*)ya = *(const float4*)&Ys[o*64 + rg];
        *(float4*)wa = *(const float4*)&Ws[o*64 + jg];
        #pragma unroll
        for (int ri = 0; ri < 4; ++ri)
            #pragma unroll
            for (int ji = 0; ji < 4; ++ji)
                acc[ri][ji] += ya[ri] * wa[ji];
    }
    float bb[4]; *(float4*)bb = *(const float4*)&b2[jg];
    float s[4] = {}, q[4] = {};
    #pragma unroll
    for (int ri = 0; ri < 4; ++ri)
        #pragma unroll
        for (int ji = 0; ji < 4; ++ji) {
            float v = acc[ri][ji] + bb[ji];
            acc[ri][ji] = v; s[ji] += v; q[ji] += v*v;
        }
    #pragma unroll
    for (int ji = 0; ji < 4; ++ji) {
        float4 v = {acc[0][ji],acc[1][ji],acc[2][ji],acc[3][ji]};
        *(float4*)&y2T[(jg+ji)*NROW + base + rg] = v;
    }
    __syncthreads();
    float* red = Ys;
    #pragma unroll
    for (int ji = 0; ji < 4; ++ji) red[(t&15)*64 + jg + ji] = s[ji];
    __syncthreads();
    if (t < 64) { float a = 0.f;
        #pragma unroll
        for (int k = 0; k < 16; ++k) a += red[k*64 + t];
        atomicAdd(&st2[t], a); }
    __syncthreads();
    #pragma unroll
    for (int ji = 0; ji < 4; ++ji) red[(t&15)*64 + jg + ji] = q[ji];
    __syncthreads();
    if (t < 64) { float a = 0.f;
        #pragma unroll
        for (int k = 0; k < 16; ++k) a += red[k*64 + t];
        atomicAdd(&st2[64 + t], a); }
}

// ------------------------------------------------------------------ GEMM3: 128 rows x 64 c / block
// out[row][c] = sum_j relu(bn2(y2T[j][row]))*MT[b][j][c] + dv[b][c]
__global__ __launch_bounds__(256) void k_gemm3(const float* __restrict__ y2T,
        const float* __restrict__ MT, const float* __restrict__ dv,
        const float* __restrict__ sc2, float* __restrict__ out) {
    __shared__ __align__(16) float Ys[64*128];   // [j][row]
    __shared__ __align__(16) float Ms[64*64];    // [j][c]
    const int t = threadIdx.x;
    const int base = blockIdx.x * 128;
    const int b = base >> 14;
    for (int f = t; f < 2048; f += 256) {        // contiguous stage + bn2 + relu
        int j = f >> 5, r4 = (f & 31) * 4;
        float4 v = *(const float4*)&y2T[j*NROW + base + r4];
        float scl = sc2[j], sh = sc2[64 + j];
        v.x = fmaxf(v.x*scl + sh, 0.f); v.y = fmaxf(v.y*scl + sh, 0.f);
        v.z = fmaxf(v.z*scl + sh, 0.f); v.w = fmaxf(v.w*scl + sh, 0.f);
        *(float4*)&Ys[j*128 + r4] = v;
    }
    for (int f = t; f < 1024; f += 256)
        *(float4*)&Ms[f*4] = *(const float4*)&MT[b*4096 + f*4];
    __syncthreads();

    const int rg = (t & 15) * 8, cg = (t >> 4) * 4;
    float acc[8][4] = {};
    #pragma unroll 4
    for (int j = 0; j < 64; ++j) {
        float ya[8], ma[4];
        *(float4*)&ya[0] = *(const float4*)&Ys[j*128 + rg];
        *(float4*)&ya[4] = *(const float4*)&Ys[j*128 + rg + 4];
        *(float4*)ma = *(const float4*)&Ms[j*64 + cg];
        #pragma unroll
        for (int ri = 0; ri < 8; ++ri)
            #pragma unroll
            for (int ci = 0; ci < 4; ++ci)
                acc[ri][ci] += ya[ri] * ma[ci];
    }
    float db[4]; *(float4*)db = *(const float4*)&dv[b*64 + cg];
    #pragma unroll
    for (int ri = 0; ri < 8; ++ri) {
        float4 v = {acc[ri][0]+db[0], acc[ri][1]+db[1], acc[ri][2]+db[2], acc[ri][3]+db[3]};
        *(float4*)&out[(base + rg + ri)*64 + cg] = v;
    }
}

// ------------------------------------------------------------------
extern "C" void kernel_launch(void* const* d_in, const int* in_sizes, int n_in,
                              void* d_out, int out_size, void* d_ws, size_t ws_size,
                              hipStream_t stream) {
    const float* lidar = (const float*)d_in[0];
    const float* img   = (const float*)d_in[1];
    const float* W1  = (const float*)d_in[2];
    const float* b1  = (const float*)d_in[3];
    const float* g1  = (const float*)d_in[4];
    const float* be1 = (const float*)d_in[5];
    const float* W2  = (const float*)d_in[6];
    const float* b2  = (const float*)d_in[7];
    const float* g2  = (const float*)d_in[8];
    const float* be2 = (const float*)d_in[9];
    const float* W3  = (const float*)d_in[10];
    const float* b3  = (const float*)d_in[11];

    float* ws   = (float*)d_ws;
    float* y1T  = ws;                    // 128*65536
    float* y2T  = y1T + 128*NROW;        // 64*65536
    float* g    = y2T + 64*NROW;         // 256
    float* c1   = g   + 256;             // 512
    float* MT   = c1  + 512;             // 16384
    float* dv   = MT  + 16384;           // 256
    float* W1hT = dv  + 256;             // 8192
    float* W2T  = W1hT + 8192;           // 8192
    float* st   = W2T + 8192;            // 384
    float* sc   = st  + 384;             // 384

    hipMemsetAsync(st, 0, 384 * sizeof(float), stream);

    k_prep <<<256,  256, 0, stream>>>(img, W3, b3, g, MT, dv);
    k_wt   <<<1,    512, 0, stream>>>(W1, W2, b1, g, W1hT, W2T, c1);
    k_gemm1<<<512,  256, 0, stream>>>(lidar, W1hT, c1, y1T, st);
    k_fin1 <<<1,    128, 0, stream>>>(st, g1, be1, sc);
    k_gemm2<<<1024, 256, 0, stream>>>(y1T, W2T, sc, b2, y2T, st + 256);
    k_fin2 <<<1,    64,  0, stream>>>(st + 256, g2, be2, sc + 256);
    k_gemm3<<<512,  256, 0, stream>>>(y2T, MT, dv, sc + 256, (float*)d_out);
}